// Round 7
// baseline (594.470 us; speedup 1.0000x reference)
//
#include <hip/hip_runtime.h>
#include <hip/hip_bf16.h>
#include <math.h>

typedef __bf16 bf16v8 __attribute__((ext_vector_type(8)));
typedef float  f32x4  __attribute__((ext_vector_type(4)));

// ---------------------------------------------------------------------------
// Kernel 1: W_img (2048x512 f32, k-major) -> Wt (512x2048 bf16, a-major)
// ---------------------------------------------------------------------------
__global__ __launch_bounds__(256) void wt_k(const float* __restrict__ W,
                                            unsigned short* __restrict__ Wt)
{
    __shared__ float tile[64][65];
    const int k0 = blockIdx.x * 64;
    const int a0 = blockIdx.y * 64;
    const int t = threadIdx.x;
    const int c = t & 63, rbase = t >> 6;
#pragma unroll
    for (int i = 0; i < 16; ++i) {
        int kr = rbase + i * 4;
        tile[kr][c] = W[(k0 + kr) * 512 + a0 + c];
    }
    __syncthreads();
#pragma unroll
    for (int i = 0; i < 16; ++i) {
        int ar = rbase + i * 4;
        Wt[(a0 + ar) * 2048 + k0 + c] =
            __builtin_bit_cast(unsigned short, (__bf16)tile[c][ar]);
    }
}

// ---------------------------------------------------------------------------
// Kernel 2: hb[b][a] = hidden[b]@W_hid[:,a] + b_hid[a] + b_img[a];
//           beta[b] = sigmoid(hidden[b]@w_beta + b_beta)
// ---------------------------------------------------------------------------
__global__ __launch_bounds__(256) void hid_k(
    const float* __restrict__ hidden, const float* __restrict__ W_hid,
    const float* __restrict__ b_hid,  const float* __restrict__ b_img,
    const float* __restrict__ w_beta, const float* __restrict__ b_beta,
    float* __restrict__ hb, float* __restrict__ betap)
{
    const int b = blockIdx.x, t = threadIdx.x;
    __shared__ float hs[512];
    __shared__ float red[4];
    hs[t]       = hidden[b * 512 + t];
    hs[t + 256] = hidden[b * 512 + 256 + t];
    __syncthreads();
    float a0 = 0.f, a1 = 0.f;
#pragma unroll 4
    for (int h = 0; h < 512; ++h) {
        float hv = hs[h];
        a0 = fmaf(hv, W_hid[h * 512 + t], a0);
        a1 = fmaf(hv, W_hid[h * 512 + 256 + t], a1);
    }
    hb[b * 512 + t]       = a0 + b_hid[t]       + b_img[t];
    hb[b * 512 + 256 + t] = a1 + b_hid[256 + t] + b_img[256 + t];

    float x = hs[t] * w_beta[t] + hs[t + 256] * w_beta[t + 256];
#pragma unroll
    for (int k = 32; k >= 1; k >>= 1) x += __shfl_xor(x, k, 64);
    const int lane = t & 63, wid = t >> 6;
    if (lane == 0) red[wid] = x;
    __syncthreads();
    if (t == 0) {
        float s = red[0] + red[1] + red[2] + red[3] + b_beta[0];
        betap[b] = 1.f / (1.f + __expf(-s));
    }
}

// ---------------------------------------------------------------------------
// Kernel 3: barrier-free direct-load scores GEMM.
//   NO LDS, NO barriers, NO manual waitcnt. Each wave owns 16 rows x 128
//   cols: A fragments loaded straight from img (fp32, coalesced 16x128B per
//   iter, cvt in reg), B fragments straight from Wt (bf16, L2-resident).
//   acc = 8 x 16x16x32 fragments. 1568 blocks x 4 independent waves; TLP
//   hides all latency -- no block-wide convoy possible.
//   Epilogue: relu(acc + hb) * w_att, 16-lane shfl col-reduce, write
//   partials[nb][row].
// ---------------------------------------------------------------------------
__global__ __launch_bounds__(256, 4) void scores_direct(
    const float* __restrict__ img,            // [25088][2048] f32
    const unsigned short* __restrict__ Wt,    // [512][2048] bf16 bits
    const float* __restrict__ hb,             // [128][512]
    const float* __restrict__ w_att,          // [512]
    float* __restrict__ partials)             // [4][25088]
{
    const int tid  = threadIdx.x;
    const int lane = tid & 63;
    const int wid  = tid >> 6;
    const int g    = lane >> 4;   // k-quarter 0..3
    const int fl   = lane & 15;

    // XCD-bijective swizzle: 1568 = 8*196; the 4 nb sharing an A-panel are
    // consecutive within an XCD chunk -> A read once per XCD L2.
    const int id = blockIdx.x;
    const int wg = (id & 7) * 196 + (id >> 3);
    const int nb    = wg & 3;     // 128-col block of A=512
    const int mtile = wg >> 2;    // 0..391 (64 rows each)
    const int r0 = mtile * 64;

    // A: lane (g,fl) reads img[r0 + wid*16 + fl][it*32 + g*8 .. +7]
    const float* gA = img + (size_t)(r0 + wid * 16 + fl) * 2048 + g * 8;
    // B fragment fn: col = nb*128 + fn*16 + fl, k-window = it*32 + g*8
    const unsigned short* gB = Wt + (size_t)(nb * 128 + fl) * 2048 + g * 8;

    f32x4 acc[8] = {};   // acc[fn], fn = 16-col group

    for (int it = 0; it < 64; ++it) {
        float4 a0 = *(const float4*)(gA + it * 32);
        float4 a1 = *(const float4*)(gA + it * 32 + 4);
        bf16v8 av;
        av[0] = (__bf16)a0.x; av[1] = (__bf16)a0.y;
        av[2] = (__bf16)a0.z; av[3] = (__bf16)a0.w;
        av[4] = (__bf16)a1.x; av[5] = (__bf16)a1.y;
        av[6] = (__bf16)a1.z; av[7] = (__bf16)a1.w;
#pragma unroll
        for (int fn = 0; fn < 8; ++fn) {
            bf16v8 bv = *(const bf16v8*)(gB + (size_t)fn * 16 * 2048 + it * 32);
            acc[fn] = __builtin_amdgcn_mfma_f32_16x16x32_bf16(av, bv, acc[fn],
                                                              0, 0, 0);
        }
    }

    // ---- epilogue: relu(acc + hb) * w_att, reduce over 128 cols ----------
    float w4[8];
#pragma unroll
    for (int fn = 0; fn < 8; ++fn) w4[fn] = w_att[nb * 128 + fn * 16 + fl];

#pragma unroll
    for (int rg = 0; rg < 4; ++rg) {
        int growC = r0 + wid * 16 + g * 4 + rg;   // this lane's acc row
        const float* hbrow = hb + (growC / 196) * 512 + nb * 128;
        float s = 0.f;
#pragma unroll
        for (int fn = 0; fn < 8; ++fn) {
            float v = acc[fn][rg] + hbrow[fn * 16 + fl];
            v = fmaxf(v, 0.f);
            s = fmaf(v, w4[fn], s);
        }
#pragma unroll
        for (int m = 1; m < 16; m <<= 1) s += __shfl_xor(s, m, 64);
        if (fl == 0) partials[nb * 25088 + growC] = s;
    }
}

// ---------------------------------------------------------------------------
// Kernel 4: softmax over N=196 per batch.
// ---------------------------------------------------------------------------
__global__ __launch_bounds__(256) void softmax_k(
    const float* __restrict__ partials, const float* __restrict__ betap,
    const float* __restrict__ b_att,
    float* __restrict__ out_w, float* __restrict__ wbeta)
{
    const int b = blockIdx.x;
    const int t = threadIdx.x;
    const int lane = t & 63, wid = t >> 6;
    __shared__ float red[4];

    float scv = 0.f, sc = -1e30f;
    if (t < 196) {
        int r = b * 196 + t;
        scv = partials[r] + partials[25088 + r] + partials[2 * 25088 + r] +
              partials[3 * 25088 + r] + b_att[0];
        sc = scv;
    }
    float m = sc;
#pragma unroll
    for (int k = 32; k >= 1; k >>= 1) m = fmaxf(m, __shfl_xor(m, k, 64));
    if (lane == 0) red[wid] = m;
    __syncthreads();
    m = fmaxf(fmaxf(red[0], red[1]), fmaxf(red[2], red[3]));

    float e = (t < 196) ? __expf(scv - m) : 0.f;
    float ssum = e;
#pragma unroll
    for (int k = 32; k >= 1; k >>= 1) ssum += __shfl_xor(ssum, k, 64);
    __syncthreads();
    if (lane == 0) red[wid] = ssum;
    __syncthreads();
    float denom = red[0] + red[1] + red[2] + red[3];

    if (t < 196) {
        float w = e / denom;
        out_w[b * 196 + t] = w;
        wbeta[b * 196 + t] = w * betap[b];
    }
}

// ---------------------------------------------------------------------------
// Kernel 5: context[b][c] = sum_n wbeta[b][n] * img[b][n][c]
// ---------------------------------------------------------------------------
__global__ __launch_bounds__(256) void ctx_k(
    const float* __restrict__ img, const float* __restrict__ wbeta,
    float* __restrict__ out)
{
    const int b = blockIdx.y;
    const int c0 = blockIdx.x * 256 + threadIdx.x;
    __shared__ float w[200];
    if (threadIdx.x < 196) w[threadIdx.x] = wbeta[b * 196 + threadIdx.x];
    __syncthreads();
    const float* base = img + (size_t)b * 196 * 2048 + c0;
    float acc = 0.f;
#pragma unroll 4
    for (int n = 0; n < 196; ++n) {
        acc = fmaf(w[n], base[(size_t)n * 2048], acc);
    }
    out[b * 2048 + c0] = acc;
}

// ---------------------------------------------------------------------------
extern "C" void kernel_launch(void* const* d_in, const int* in_sizes, int n_in,
                              void* d_out, int out_size, void* d_ws, size_t ws_size,
                              hipStream_t stream)
{
    const float* img    = (const float*)d_in[0];
    const float* hidden = (const float*)d_in[1];
    const float* W_img  = (const float*)d_in[2];
    const float* b_img  = (const float*)d_in[3];
    const float* W_hid  = (const float*)d_in[4];
    const float* b_hid  = (const float*)d_in[5];
    const float* w_att  = (const float*)d_in[6];
    const float* b_att  = (const float*)d_in[7];
    const float* w_beta = (const float*)d_in[8];
    const float* b_beta = (const float*)d_in[9];

    char* ws = (char*)d_ws;
    unsigned short* Wt = (unsigned short*)ws;            // [512][2048] bf16: 2 MB
    float* hbp   = (float*)(ws + 2097152);               // [128][512]
    float* betap = (float*)(ws + 2359296);               // [128]
    float* parts = (float*)(ws + 2359808);               // [4][25088]
    float* wbeta = (float*)(ws + 2761216);               // [128][196]

    float* out_ctx = (float*)d_out;                      // [128][2048]
    float* out_w   = out_ctx + 128 * 2048;               // [128][196]

    wt_k<<<dim3(32, 8), 256, 0, stream>>>(W_img, Wt);
    hid_k<<<128, 256, 0, stream>>>(hidden, W_hid, b_hid, b_img, w_beta, b_beta,
                                   hbp, betap);
    scores_direct<<<1568, 256, 0, stream>>>(img, Wt, hbp, w_att, parts);
    softmax_k<<<128, 256, 0, stream>>>(parts, betap, b_att, out_w, wbeta);
    ctx_k<<<dim3(8, 128), 256, 0, stream>>>(img, wbeta, out_ctx);
}

// Round 8
// 210.892 us; speedup vs baseline: 2.8188x; 2.8188x over previous
//
#include <hip/hip_runtime.h>
#include <hip/hip_bf16.h>
#include <math.h>

typedef __bf16 bf16v8 __attribute__((ext_vector_type(8)));
typedef __bf16 bf16v4 __attribute__((ext_vector_type(4)));
typedef float  f32x4  __attribute__((ext_vector_type(4)));

__device__ __forceinline__ void gload_lds16(const void* g, void* l) {
    __builtin_amdgcn_global_load_lds(
        (const __attribute__((address_space(1))) unsigned int*)g,
        (__attribute__((address_space(3))) unsigned int*)l, 16, 0, 0);
}

// convert 4 fp32 -> 4 bf16, store one b64
__device__ __forceinline__ void cvt_w4(void* dst, float4 a) {
    bf16v4 v;
    v[0] = (__bf16)a.x; v[1] = (__bf16)a.y;
    v[2] = (__bf16)a.z; v[3] = (__bf16)a.w;
    *(bf16v4*)dst = v;
}

// ---------------------------------------------------------------------------
// Kernel 1: W_img (2048x512 f32, k-major) -> Wt (512x2048 bf16, a-major)
// ---------------------------------------------------------------------------
__global__ __launch_bounds__(256) void wt_k(const float* __restrict__ W,
                                            unsigned short* __restrict__ Wt)
{
    __shared__ float tile[64][65];
    const int k0 = blockIdx.x * 64;
    const int a0 = blockIdx.y * 64;
    const int t = threadIdx.x;
    const int c = t & 63, rbase = t >> 6;
#pragma unroll
    for (int i = 0; i < 16; ++i) {
        int kr = rbase + i * 4;
        tile[kr][c] = W[(k0 + kr) * 512 + a0 + c];
    }
    __syncthreads();
#pragma unroll
    for (int i = 0; i < 16; ++i) {
        int ar = rbase + i * 4;
        Wt[(a0 + ar) * 2048 + k0 + c] =
            __builtin_bit_cast(unsigned short, (__bf16)tile[c][ar]);
    }
}

// ---------------------------------------------------------------------------
// Kernel 2: hb[b][a] = hidden[b]@W_hid[:,a] + b_hid[a] + b_img[a];
//           beta[b] = sigmoid(hidden[b]@w_beta + b_beta)
// ---------------------------------------------------------------------------
__global__ __launch_bounds__(256) void hid_k(
    const float* __restrict__ hidden, const float* __restrict__ W_hid,
    const float* __restrict__ b_hid,  const float* __restrict__ b_img,
    const float* __restrict__ w_beta, const float* __restrict__ b_beta,
    float* __restrict__ hb, float* __restrict__ betap)
{
    const int b = blockIdx.x, t = threadIdx.x;
    __shared__ float hs[512];
    __shared__ float red[4];
    hs[t]       = hidden[b * 512 + t];
    hs[t + 256] = hidden[b * 512 + 256 + t];
    __syncthreads();
    float a0 = 0.f, a1 = 0.f;
#pragma unroll 4
    for (int h = 0; h < 512; ++h) {
        float hv = hs[h];
        a0 = fmaf(hv, W_hid[h * 512 + t], a0);
        a1 = fmaf(hv, W_hid[h * 512 + 256 + t], a1);
    }
    hb[b * 512 + t]       = a0 + b_hid[t]       + b_img[t];
    hb[b * 512 + 256 + t] = a1 + b_hid[256 + t] + b_img[256 + t];

    float x = hs[t] * w_beta[t] + hs[t + 256] * w_beta[t + 256];
#pragma unroll
    for (int k = 32; k >= 1; k >>= 1) x += __shfl_xor(x, k, 64);
    const int lane = t & 63, wid = t >> 6;
    if (lane == 0) red[wid] = x;
    __syncthreads();
    if (t == 0) {
        float s = red[0] + red[1] + red[2] + red[3] + b_beta[0];
        betap[b] = 1.f / (1.f + __expf(-s));
    }
}

// ---------------------------------------------------------------------------
// Kernel 3: fused scores GEMM, m97-parity LDS bytes.
//   128x128 tile, BK=32, 4 waves, grid 784 (196 mtiles x 4 col-blocks).
//   A: fp32 global -> regs (COALESCED: 4 lanes/row, 16 full lines/instr)
//      -> cvt bf16 -> ds_write_b64 into [128][80B] padded tile (conflict-free
//      b128 frag reads). Per K-step/block: 32KB reads + 16KB writes = m97's
//      48KB (r2-r6 moved 72-96KB -> the 13% MfmaUtil plateau).
//   B: global_load_lds bf16 [128][64B], source XOR swizzle (conflict-free).
//   Schedule = r5's proven skeleton: counted vmcnt(4) barrier, 2-deep A regs.
// ---------------------------------------------------------------------------
__global__ __launch_bounds__(256, 3) void scores_gemm(
    const float* __restrict__ img,            // [25088][2048] f32
    const unsigned short* __restrict__ Wt,    // [512][2048] bf16 bits
    const float* __restrict__ hb,             // [128][512]
    const float* __restrict__ w_att,          // [512]
    float* __restrict__ partials)             // [4][25088]
{
    __shared__ __align__(16) char smem[36864];
    char* A0 = smem;            // 128*80 = 10240
    char* A1 = smem + 10240;
    char* B0 = smem + 20480;    // 128*64 = 8192
    char* B1 = smem + 28672;

    const int tid  = threadIdx.x;
    const int lane = tid & 63;
    const int wid  = tid >> 6;
    const int wm   = wid >> 1;   // 0..1 (64-row half)
    const int wn   = wid & 1;    // 0..1 (64-col half)

    // XCD-bijective swizzle: 784 = 8*98
    const int id = blockIdx.x;
    const int wg = (id & 7) * 98 + (id >> 3);
    const int cb    = wg & 3;
    const int mtile = wg >> 2;   // 0..195
    const int r0 = mtile * 128;
    const int a0 = cb * 128;

    // A staging: thread -> rows ar, ar+64; fp32 cols ac..ac+3 and +16..+19.
    // Per instr: 4 lanes x 16B cover one row's 64B -> 16 full lines/wave.
    const int ar = tid >> 2;          // 0..63
    const int ac = (tid & 3) * 4;     // 0,4,8,12
    const float* gA0 = img + (size_t)(r0 + ar) * 2048 + ac;
    const float* gA1 = img + (size_t)(r0 + 64 + ar) * 2048 + ac;
    const int aW0 = ar * 80 + ac * 2;         // bf16 LDS bytes
    const int aW1 = (64 + ar) * 80 + ac * 2;

    // B staging: gload_lds linear dest tid*16; source pre-swizzled
    const int bswz = ((tid & 3) ^ ((tid >> 3) & 3)) * 8;
    const unsigned short* gB0 = Wt + (size_t)(a0 + (tid >> 2)) * 2048 + bswz;
    const unsigned short* gB1 = Wt + (size_t)(a0 + 64 + (tid >> 2)) * 2048 + bswz;
    const int bW0 = tid * 16;
    const int bW1 = 4096 + tid * 16;

    const int g  = lane >> 4;
    const int fl = lane & 15;
    const int bro = (g ^ ((fl >> 1) & 3)) << 4;   // B read XOR offset

    f32x4 acc[4][4] = {};
    float4 rA0[4], rA1[4];

#define ALOAD(RC, IT) do {                                                   \
    RC[0] = *(const float4*)(gA0 + (IT) * 32);                               \
    RC[1] = *(const float4*)(gA0 + (IT) * 32 + 16);                          \
    RC[2] = *(const float4*)(gA1 + (IT) * 32);                               \
    RC[3] = *(const float4*)(gA1 + (IT) * 32 + 16);                          \
} while (0)

#define ACVT(DST, RC) do {                                                   \
    cvt_w4(DST + aW0,      RC[0]);                                           \
    cvt_w4(DST + aW0 + 32, RC[1]);                                           \
    cvt_w4(DST + aW1,      RC[2]);                                           \
    cvt_w4(DST + aW1 + 32, RC[3]);                                           \
} while (0)

    // ---------------- prologue (full-drain, safe) --------------------------
    ALOAD(rA0, 0);
    gload_lds16(gB0, B0 + bW0);
    gload_lds16(gB1, B0 + bW1);
    __builtin_amdgcn_sched_barrier(0);
    ACVT(A0, rA0);                         // A(0) -> LDS A0
    ALOAD(rA0, 1);                         // Ad(1)
    ALOAD(rA1, 2);                         // Ad(2)
    __syncthreads();                       // full drain: everything staged

// body K: frags from CA/CB; stage B(K+1)->NB; cvt RC (holds A(K+1)) -> NA;
// reload RC <- Ad(K+3). Counted barrier vmcnt(4): queue at barrier =
// [Ad(K+2)x4, B(K+1)x2, Ad(K+3)x4] -> retires Ad(K+2)+B(K+1), keeps Ad(K+3).
#define BODY(K, CA, CB, NA, NB, RC, STAGE, RELOAD, FULLBAR) do {             \
    bf16v8 av[4], bv[4];                                                     \
    _Pragma("unroll")                                                        \
    for (int fm = 0; fm < 4; ++fm) {                                         \
        int row = wm * 64 + fm * 16 + fl;                                    \
        av[fm] = *(const bf16v8*)(CA + row * 80 + g * 16);                   \
    }                                                                        \
    _Pragma("unroll")                                                        \
    for (int fn = 0; fn < 4; ++fn) {                                         \
        int col = wn * 64 + fn * 16 + fl;                                    \
        bv[fn] = *(const bf16v8*)(CB + col * 64 + bro);                      \
    }                                                                        \
    if (STAGE) {                                                             \
        gload_lds16(gB0 + (K + 1) * 32, NB + bW0);                           \
        gload_lds16(gB1 + (K + 1) * 32, NB + bW1);                           \
    }                                                                        \
    __builtin_amdgcn_sched_barrier(0);                                       \
    if (STAGE) ACVT(NA, RC);                                                 \
    if (RELOAD) ALOAD(RC, K + 3);                                            \
    __builtin_amdgcn_sched_barrier(0);                                       \
    _Pragma("unroll")                                                        \
    for (int fm = 0; fm < 4; ++fm)                                           \
        _Pragma("unroll")                                                    \
        for (int fn = 0; fn < 4; ++fn)                                       \
            acc[fm][fn] = __builtin_amdgcn_mfma_f32_16x16x32_bf16(           \
                av[fm], bv[fn], acc[fm][fn], 0, 0, 0);                       \
    if (FULLBAR) {                                                           \
        __syncthreads();                                                     \
    } else {                                                                 \
        __builtin_amdgcn_sched_barrier(0);                                   \
        asm volatile("s_waitcnt vmcnt(4) lgkmcnt(0)" ::: "memory");          \
        __builtin_amdgcn_s_barrier();                                        \
        __builtin_amdgcn_sched_barrier(0);                                   \
    }                                                                        \
} while (0)

    // ---------------- main loop: bodies 0..59, counted barriers -----------
    for (int t = 0; t < 60; t += 2) {
        BODY(t,     A0, B0, A1, B1, rA0, true, true, false);
        BODY(t + 1, A1, B1, A0, B0, rA1, true, true, false);
    }
    // ---------------- tail: bodies 60..63 ---------------------------------
    BODY(60, A0, B0, A1, B1, rA0, true,  true,  false);  // reloads Ad(63)
    BODY(61, A1, B1, A0, B0, rA1, true,  false, true);
    BODY(62, A0, B0, A1, B1, rA0, true,  false, true);   // cvt A(63)
    BODY(63, A1, B1, A0, B0, rA1, false, false, true);
#undef BODY
#undef ALOAD
#undef ACVT

    // ---------------- epilogue: relu(acc + hb) * w_att, col-reduce --------
    float* red = (float*)smem;   // [2][128]
    const int l4 = lane >> 4;

    float w4[4];
#pragma unroll
    for (int fn = 0; fn < 4; ++fn) w4[fn] = w_att[a0 + wn * 64 + fn * 16 + fl];

#pragma unroll
    for (int fm = 0; fm < 4; ++fm) {
#pragma unroll
        for (int rg = 0; rg < 4; ++rg) {
            int row = wm * 64 + fm * 16 + l4 * 4 + rg;
            int grow = r0 + row;
            int bb = grow / 196;
            const float* hbrow = hb + bb * 512 + a0 + wn * 64;
            float s = 0.f;
#pragma unroll
            for (int fn = 0; fn < 4; ++fn) {
                float v = acc[fm][fn][rg] + hbrow[fn * 16 + fl];
                v = fmaxf(v, 0.f);
                s = fmaf(v, w4[fn], s);
            }
#pragma unroll
            for (int m = 1; m < 16; m <<= 1) s += __shfl_xor(s, m, 64);
            if (fl == 0) red[wn * 128 + row] = s;
        }
    }
    __syncthreads();
    if (tid < 128) {
        partials[cb * 25088 + r0 + tid] = red[tid] + red[128 + tid];
    }
}

// ---------------------------------------------------------------------------
// Kernel 4: softmax over N=196 per batch.
// ---------------------------------------------------------------------------
__global__ __launch_bounds__(256) void softmax_k(
    const float* __restrict__ partials, const float* __restrict__ betap,
    const float* __restrict__ b_att,
    float* __restrict__ out_w, float* __restrict__ wbeta)
{
    const int b = blockIdx.x;
    const int t = threadIdx.x;
    const int lane = t & 63, wid = t >> 6;
    __shared__ float red[4];

    float scv = 0.f, sc = -1e30f;
    if (t < 196) {
        int r = b * 196 + t;
        scv = partials[r] + partials[25088 + r] + partials[2 * 25088 + r] +
              partials[3 * 25088 + r] + b_att[0];
        sc = scv;
    }
    float m = sc;
#pragma unroll
    for (int k = 32; k >= 1; k >>= 1) m = fmaxf(m, __shfl_xor(m, k, 64));
    if (lane == 0) red[wid] = m;
    __syncthreads();
    m = fmaxf(fmaxf(red[0], red[1]), fmaxf(red[2], red[3]));

    float e = (t < 196) ? __expf(scv - m) : 0.f;
    float ssum = e;
#pragma unroll
    for (int k = 32; k >= 1; k >>= 1) ssum += __shfl_xor(ssum, k, 64);
    __syncthreads();
    if (lane == 0) red[wid] = ssum;
    __syncthreads();
    float denom = red[0] + red[1] + red[2] + red[3];

    if (t < 196) {
        float w = e / denom;
        out_w[b * 196 + t] = w;
        wbeta[b * 196 + t] = w * betap[b];
    }
}

// ---------------------------------------------------------------------------
// Kernel 5: context[b][c] = sum_n wbeta[b][n] * img[b][n][c]
// ---------------------------------------------------------------------------
__global__ __launch_bounds__(256) void ctx_k(
    const float* __restrict__ img, const float* __restrict__ wbeta,
    float* __restrict__ out)
{
    const int b = blockIdx.y;
    const int c0 = blockIdx.x * 512 + threadIdx.x * 2;
    __shared__ float w[200];
    if (threadIdx.x < 196) w[threadIdx.x] = wbeta[b * 196 + threadIdx.x];
    __syncthreads();
    const float* base = img + (size_t)b * 196 * 2048 + c0;
    float acx = 0.f, acy = 0.f;
#pragma unroll 4
    for (int n = 0; n < 196; ++n) {
        float2 v = *(const float2*)(base + (size_t)n * 2048);
        float wn = w[n];
        acx = fmaf(wn, v.x, acx);
        acy = fmaf(wn, v.y, acy);
    }
    float2 r; r.x = acx; r.y = acy;
    *(float2*)(out + b * 2048 + c0) = r;
}

// ---------------------------------------------------------------------------
extern "C" void kernel_launch(void* const* d_in, const int* in_sizes, int n_in,
                              void* d_out, int out_size, void* d_ws, size_t ws_size,
                              hipStream_t stream)
{
    const float* img    = (const float*)d_in[0];
    const float* hidden = (const float*)d_in[1];
    const float* W_img  = (const float*)d_in[2];
    const float* b_img  = (const float*)d_in[3];
    const float* W_hid  = (const float*)d_in[4];
    const float* b_hid  = (const float*)d_in[5];
    const float* w_att  = (const float*)d_in[6];
    const float* b_att  = (const float*)d_in[7];
    const float* w_beta = (const float*)d_in[8];
    const float* b_beta = (const float*)d_in[9];

    char* ws = (char*)d_ws;
    unsigned short* Wt = (unsigned short*)ws;            // [512][2048] bf16: 2 MB
    float* hbp   = (float*)(ws + 2097152);               // [128][512]
    float* betap = (float*)(ws + 2359296);               // [128]
    float* parts = (float*)(ws + 2359808);               // [4][25088]
    float* wbeta = (float*)(ws + 2761216);               // [128][196]

    float* out_ctx = (float*)d_out;                      // [128][2048]
    float* out_w   = out_ctx + 128 * 2048;               // [128][196]

    wt_k<<<dim3(32, 8), 256, 0, stream>>>(W_img, Wt);
    hid_k<<<128, 256, 0, stream>>>(hidden, W_hid, b_hid, b_img, w_beta, b_beta,
                                   hbp, betap);
    scores_gemm<<<784, 256, 0, stream>>>(img, Wt, hbp, w_att, parts);
    softmax_k<<<128, 256, 0, stream>>>(parts, betap, b_att, out_w, wbeta);
    ctx_k<<<dim3(4, 128), 256, 0, stream>>>(img, wbeta, out_ctx);
}

// Round 9
// 193.743 us; speedup vs baseline: 3.0683x; 1.0885x over previous
//
#include <hip/hip_runtime.h>
#include <hip/hip_bf16.h>
#include <math.h>

typedef __bf16 bf16v8 __attribute__((ext_vector_type(8)));
typedef float  f32x4  __attribute__((ext_vector_type(4)));

__device__ __forceinline__ void gload_lds16(const void* g, void* l) {
    __builtin_amdgcn_global_load_lds(
        (const __attribute__((address_space(1))) unsigned int*)g,
        (__attribute__((address_space(3))) unsigned int*)l, 16, 0, 0);
}

// convert 8 fp32 -> 8 bf16, store one aligned b128
__device__ __forceinline__ void cvt_store8(void* dst, float4 a, float4 b) {
    bf16v8 v;
    v[0] = (__bf16)a.x; v[1] = (__bf16)a.y; v[2] = (__bf16)a.z; v[3] = (__bf16)a.w;
    v[4] = (__bf16)b.x; v[5] = (__bf16)b.y; v[6] = (__bf16)b.z; v[7] = (__bf16)b.w;
    *(bf16v8*)dst = v;
}

// ---------------------------------------------------------------------------
// Kernel 1: W_img (2048x512 f32, k-major) -> Wt (512x2048 bf16, a-major)
// ---------------------------------------------------------------------------
__global__ __launch_bounds__(256) void wt_k(const float* __restrict__ W,
                                            unsigned short* __restrict__ Wt)
{
    __shared__ float tile[64][65];
    const int k0 = blockIdx.x * 64;
    const int a0 = blockIdx.y * 64;
    const int t = threadIdx.x;
    const int c = t & 63, rbase = t >> 6;
#pragma unroll
    for (int i = 0; i < 16; ++i) {
        int kr = rbase + i * 4;
        tile[kr][c] = W[(k0 + kr) * 512 + a0 + c];
    }
    __syncthreads();
#pragma unroll
    for (int i = 0; i < 16; ++i) {
        int ar = rbase + i * 4;
        Wt[(a0 + ar) * 2048 + k0 + c] =
            __builtin_bit_cast(unsigned short, (__bf16)tile[c][ar]);
    }
}

// ---------------------------------------------------------------------------
// Kernel 2: hb[b][a] = hidden[b]@W_hid[:,a] + b_hid[a] + b_img[a];
//           beta[b] = sigmoid(hidden[b]@w_beta + b_beta)
// ---------------------------------------------------------------------------
__global__ __launch_bounds__(256) void hid_k(
    const float* __restrict__ hidden, const float* __restrict__ W_hid,
    const float* __restrict__ b_hid,  const float* __restrict__ b_img,
    const float* __restrict__ w_beta, const float* __restrict__ b_beta,
    float* __restrict__ hb, float* __restrict__ betap)
{
    const int b = blockIdx.x, t = threadIdx.x;
    __shared__ float hs[512];
    __shared__ float red[4];
    hs[t]       = hidden[b * 512 + t];
    hs[t + 256] = hidden[b * 512 + 256 + t];
    __syncthreads();
    float a0 = 0.f, a1 = 0.f;
#pragma unroll 4
    for (int h = 0; h < 512; ++h) {
        float hv = hs[h];
        a0 = fmaf(hv, W_hid[h * 512 + t], a0);
        a1 = fmaf(hv, W_hid[h * 512 + 256 + t], a1);
    }
    hb[b * 512 + t]       = a0 + b_hid[t]       + b_img[t];
    hb[b * 512 + 256 + t] = a1 + b_hid[256 + t] + b_img[256 + t];

    float x = hs[t] * w_beta[t] + hs[t + 256] * w_beta[t + 256];
#pragma unroll
    for (int k = 32; k >= 1; k >>= 1) x += __shfl_xor(x, k, 64);
    const int lane = t & 63, wid = t >> 6;
    if (lane == 0) red[wid] = x;
    __syncthreads();
    if (t == 0) {
        float s = red[0] + red[1] + red[2] + red[3] + b_beta[0];
        betap[b] = 1.f / (1.f + __expf(-s));
    }
}

// ---------------------------------------------------------------------------
// Kernel 3: fused scores GEMM — merged bodies (2 K-steps per barrier).
//   128x128 tile, 4 waves, grid 784. 32 sync-bodies instead of 64: the
//   r2..r8 plateau showed ~2300cy serialized per barrier-body regardless of
//   schedule; merged bodies halve the count and their ~1100cy of work covers
//   HBM latency of loads issued at body top even with full-drain barriers.
//   Plain __syncthreads only; no inline asm.
//   A: fp32 global -> regs (depth-2) -> cvt bf16 -> [128][64B] (stride-64
//      b128 reads/writes = free 2-way aliasing), 4 buffers.
//   B: global_load_lds bf16 [128][64B] + proven source XOR swizzle, 4 bufs.
//   LDS = 8 x 8KB = 64KB exactly -> 2 blocks/CU. (256,2): no spills.
// ---------------------------------------------------------------------------
__global__ __launch_bounds__(256, 2) void scores_gemm(
    const float* __restrict__ img,            // [25088][2048] f32
    const unsigned short* __restrict__ Wt,    // [512][2048] bf16 bits
    const float* __restrict__ hb,             // [128][512]
    const float* __restrict__ w_att,          // [512]
    float* __restrict__ partials)             // [4][25088]
{
    __shared__ __align__(16) char smem[65536];
    char* A0 = smem;            // [128][64] bf16 per K-step
    char* A1 = smem + 8192;
    char* A2 = smem + 16384;
    char* A3 = smem + 24576;
    char* B0 = smem + 32768;    // [128 cols][64B] per K-step
    char* B1 = smem + 40960;
    char* B2 = smem + 49152;
    char* B3 = smem + 57344;

    const int tid  = threadIdx.x;
    const int lane = tid & 63;
    const int wid  = tid >> 6;
    const int wm   = wid >> 1;   // 0..1 (64-row half)
    const int wn   = wid & 1;    // 0..1 (64-col half)

    // XCD-bijective swizzle: 784 = 8*98
    const int id = blockIdx.x;
    const int wg = (id & 7) * 98 + (id >> 3);
    const int cb    = wg & 3;
    const int mtile = wg >> 2;   // 0..195
    const int r0 = mtile * 128;
    const int a0 = cb * 128;

    // A staging: thread -> rows ar, ar+64; k-octet aq (8 consecutive fp32)
    const int ar = tid >> 2;          // 0..63
    const int aq = tid & 3;           // octet
    const float* gA0 = img + (size_t)(r0 + ar) * 2048 + aq * 8;
    const float* gA1 = img + (size_t)(r0 + 64 + ar) * 2048 + aq * 8;
    const int aW0 = ar * 64 + aq * 16;          // b128 dest, row ar
    const int aW1 = (64 + ar) * 64 + aq * 16;   // row ar+64

    // B staging (r8-proven): gload_lds linear dest tid*16; source pre-swizzled
    const int bswz = ((tid & 3) ^ ((tid >> 3) & 3)) * 8;
    const unsigned short* gB0 = Wt + (size_t)(a0 + (tid >> 2)) * 2048 + bswz;
    const unsigned short* gB1 = Wt + (size_t)(a0 + 64 + (tid >> 2)) * 2048 + bswz;
    const int bW0 = tid * 16;
    const int bW1 = 4096 + tid * 16;

    const int g  = lane >> 4;
    const int fl = lane & 15;
    const int bro = (g ^ ((fl >> 1) & 3)) << 4;   // B read XOR offset

    f32x4 acc[4][4] = {};
    float4 rA0[4], rA1[4];

#define ALOAD(RC, K) do {                                                    \
    RC[0] = *(const float4*)(gA0 + (K) * 32);                                \
    RC[1] = *(const float4*)(gA0 + (K) * 32 + 4);                            \
    RC[2] = *(const float4*)(gA1 + (K) * 32);                                \
    RC[3] = *(const float4*)(gA1 + (K) * 32 + 4);                            \
} while (0)

#define ACVT(DST, RC) do {                                                   \
    cvt_store8(DST + aW0, RC[0], RC[1]);                                     \
    cvt_store8(DST + aW1, RC[2], RC[3]);                                     \
} while (0)

#define MSTEP(CA, CB) do {                                                   \
    bf16v8 av[4], bv[4];                                                     \
    _Pragma("unroll")                                                        \
    for (int fm = 0; fm < 4; ++fm)                                           \
        av[fm] = *(const bf16v8*)(CA + (wm * 64 + fm * 16 + fl) * 64 + g * 16);\
    _Pragma("unroll")                                                        \
    for (int fn = 0; fn < 4; ++fn)                                           \
        bv[fn] = *(const bf16v8*)(CB + (wn * 64 + fn * 16 + fl) * 64 + bro); \
    _Pragma("unroll")                                                        \
    for (int fm = 0; fm < 4; ++fm)                                           \
        _Pragma("unroll")                                                    \
        for (int fn = 0; fn < 4; ++fn)                                       \
            acc[fm][fn] = __builtin_amdgcn_mfma_f32_16x16x32_bf16(           \
                av[fm], bv[fn], acc[fm][fn], 0, 0, 0);                       \
} while (0)

// merged body: consume K-steps K (CA0/CB0) and K+1 (CA1/CB1);
// stage K+2 -> NA0/NB0, K+3 -> NA1/NB1; reload regs with data K+4, K+5.
#define BODYP(K, CA0, CB0, CA1, CB1, NA0, NB0, NA1, NB1, STAGE, RELOAD, SYNC)\
do {                                                                         \
    if (STAGE) {                                                             \
        gload_lds16(gB0 + (K + 2) * 32, NB0 + bW0);                          \
        gload_lds16(gB1 + (K + 2) * 32, NB0 + bW1);                          \
        gload_lds16(gB0 + (K + 3) * 32, NB1 + bW0);                          \
        gload_lds16(gB1 + (K + 3) * 32, NB1 + bW1);                          \
        ACVT(NA0, rA0);                                                      \
        ACVT(NA1, rA1);                                                      \
    }                                                                        \
    if (RELOAD) {                                                            \
        ALOAD(rA0, K + 4);                                                   \
        ALOAD(rA1, K + 5);                                                   \
    }                                                                        \
    MSTEP(CA0, CB0);                                                         \
    MSTEP(CA1, CB1);                                                         \
    if (SYNC) __syncthreads();                                               \
} while (0)

    // ---------------- prologue ----------------
    ALOAD(rA0, 0);
    ALOAD(rA1, 1);
    gload_lds16(gB0, B0 + bW0);        // B(0)
    gload_lds16(gB1, B0 + bW1);
    gload_lds16(gB0 + 32, B1 + bW0);   // B(1)
    gload_lds16(gB1 + 32, B1 + bW1);
    ACVT(A0, rA0);                     // A(0), A(1)
    ACVT(A1, rA1);
    ALOAD(rA0, 2);
    ALOAD(rA1, 3);
    __syncthreads();

    // ---------------- main loop: bodies for K-pairs 0..59 -----------------
    for (int k = 0; k < 60; k += 4) {
        BODYP(k,     A0, B0, A1, B1, A2, B2, A3, B3, true, true, true);
        BODYP(k + 2, A2, B2, A3, B3, A0, B0, A1, B1, true, true, true);
    }
    // ---------------- tail ------------------------------------------------
    BODYP(60, A0, B0, A1, B1, A2, B2, A3, B3, true,  false, true);
    BODYP(62, A2, B2, A3, B3, A0, B0, A1, B1, false, false, false);
#undef BODYP
#undef MSTEP
#undef ACVT
#undef ALOAD

    // ---------------- epilogue: relu(acc + hb) * w_att, col-reduce --------
    float* red = (float*)smem;   // [2][128] (A0 region; dead after body 60's sync)
    const int l4 = lane >> 4;

    float w4[4];
#pragma unroll
    for (int fn = 0; fn < 4; ++fn) w4[fn] = w_att[a0 + wn * 64 + fn * 16 + fl];

#pragma unroll
    for (int fm = 0; fm < 4; ++fm) {
#pragma unroll
        for (int rg = 0; rg < 4; ++rg) {
            int row = wm * 64 + fm * 16 + l4 * 4 + rg;
            int grow = r0 + row;
            int bb = grow / 196;
            const float* hbrow = hb + bb * 512 + a0 + wn * 64;
            float s = 0.f;
#pragma unroll
            for (int fn = 0; fn < 4; ++fn) {
                float v = acc[fm][fn][rg] + hbrow[fn * 16 + fl];
                v = fmaxf(v, 0.f);
                s = fmaf(v, w4[fn], s);
            }
#pragma unroll
            for (int m = 1; m < 16; m <<= 1) s += __shfl_xor(s, m, 64);
            if (fl == 0) red[wn * 128 + row] = s;
        }
    }
    __syncthreads();
    if (tid < 128) {
        partials[cb * 25088 + r0 + tid] = red[tid] + red[128 + tid];
    }
}

// ---------------------------------------------------------------------------
// Kernel 4: softmax over N=196 per batch.
// ---------------------------------------------------------------------------
__global__ __launch_bounds__(256) void softmax_k(
    const float* __restrict__ partials, const float* __restrict__ betap,
    const float* __restrict__ b_att,
    float* __restrict__ out_w, float* __restrict__ wbeta)
{
    const int b = blockIdx.x;
    const int t = threadIdx.x;
    const int lane = t & 63, wid = t >> 6;
    __shared__ float red[4];

    float scv = 0.f, sc = -1e30f;
    if (t < 196) {
        int r = b * 196 + t;
        scv = partials[r] + partials[25088 + r] + partials[2 * 25088 + r] +
              partials[3 * 25088 + r] + b_att[0];
        sc = scv;
    }
    float m = sc;
#pragma unroll
    for (int k = 32; k >= 1; k >>= 1) m = fmaxf(m, __shfl_xor(m, k, 64));
    if (lane == 0) red[wid] = m;
    __syncthreads();
    m = fmaxf(fmaxf(red[0], red[1]), fmaxf(red[2], red[3]));

    float e = (t < 196) ? __expf(scv - m) : 0.f;
    float ssum = e;
#pragma unroll
    for (int k = 32; k >= 1; k >>= 1) ssum += __shfl_xor(ssum, k, 64);
    __syncthreads();
    if (lane == 0) red[wid] = ssum;
    __syncthreads();
    float denom = red[0] + red[1] + red[2] + red[3];

    if (t < 196) {
        float w = e / denom;
        out_w[b * 196 + t] = w;
        wbeta[b * 196 + t] = w * betap[b];
    }
}

// ---------------------------------------------------------------------------
// Kernel 5: context[b][c] = sum_n wbeta[b][n] * img[b][n][c]
// ---------------------------------------------------------------------------
__global__ __launch_bounds__(256) void ctx_k(
    const float* __restrict__ img, const float* __restrict__ wbeta,
    float* __restrict__ out)
{
    const int b = blockIdx.y;
    const int c0 = blockIdx.x * 512 + threadIdx.x * 2;
    __shared__ float w[200];
    if (threadIdx.x < 196) w[threadIdx.x] = wbeta[b * 196 + threadIdx.x];
    __syncthreads();
    const float* base = img + (size_t)b * 196 * 2048 + c0;
    float acx = 0.f, acy = 0.f;
#pragma unroll 4
    for (int n = 0; n < 196; ++n) {
        float2 v = *(const float2*)(base + (size_t)n * 2048);
        float wn = w[n];
        acx = fmaf(wn, v.x, acx);
        acy = fmaf(wn, v.y, acy);
    }
    float2 r; r.x = acx; r.y = acy;
    *(float2*)(out + b * 2048 + c0) = r;
}

// ---------------------------------------------------------------------------
extern "C" void kernel_launch(void* const* d_in, const int* in_sizes, int n_in,
                              void* d_out, int out_size, void* d_ws, size_t ws_size,
                              hipStream_t stream)
{
    const float* img    = (const float*)d_in[0];
    const float* hidden = (const float*)d_in[1];
    const float* W_img  = (const float*)d_in[2];
    const float* b_img  = (const float*)d_in[3];
    const float* W_hid  = (const float*)d_in[4];
    const float* b_hid  = (const float*)d_in[5];
    const float* w_att  = (const float*)d_in[6];
    const float* b_att  = (const float*)d_in[7];
    const float* w_beta = (const float*)d_in[8];
    const float* b_beta = (const float*)d_in[9];

    char* ws = (char*)d_ws;
    unsigned short* Wt = (unsigned short*)ws;            // [512][2048] bf16: 2 MB
    float* hbp   = (float*)(ws + 2097152);               // [128][512]
    float* betap = (float*)(ws + 2359296);               // [128]
    float* parts = (float*)(ws + 2359808);               // [4][25088]
    float* wbeta = (float*)(ws + 2761216);               // [128][196]

    float* out_ctx = (float*)d_out;                      // [128][2048]
    float* out_w   = out_ctx + 128 * 2048;               // [128][196]

    wt_k<<<dim3(32, 8), 256, 0, stream>>>(W_img, Wt);
    hid_k<<<128, 256, 0, stream>>>(hidden, W_hid, b_hid, b_img, w_beta, b_beta,
                                   hbp, betap);
    scores_gemm<<<784, 256, 0, stream>>>(img, Wt, hbp, w_att, parts);
    softmax_k<<<128, 256, 0, stream>>>(parts, betap, b_att, out_w, wbeta);
    ctx_k<<<dim3(4, 128), 256, 0, stream>>>(img, wbeta, out_ctx);
}